// Round 1
// baseline (628.977 us; speedup 1.0000x reference)
//
#include <hip/hip_runtime.h>
#include <hip/hip_bf16.h>

#define B_ 16
#define T_ 4096
#define TREG 4088
#define D_ 768
#define NSS 8
#define INNER_ 192
#define NK 1536
#define NCHUNK 128

typedef unsigned int u32;
typedef unsigned short u16;
typedef __attribute__((ext_vector_type(8))) short bf16x8;
typedef __attribute__((ext_vector_type(4))) float f32x4;

__device__ __forceinline__ u16 f2bf(float f) {
  union { __hip_bfloat16 h; u16 u; } cv;
  cv.h = __float2bfloat16(f);
  return cv.u;
}

// async global->LDS, 16B per lane. LDS dest is wave-uniform base + lane*16.
__device__ __forceinline__ void load16_lds(const void* g, void* l) {
  __builtin_amdgcn_global_load_lds(
      (const __attribute__((address_space(1))) u32*)(unsigned long long)g,
      (__attribute__((address_space(3))) u32*)(u32)(unsigned long long)l,
      16, 0, 0);
}

// ---------------- K0: Wv (768x768, k-major) -> WvT bf16 (n-major) ----------
__global__ __launch_bounds__(256) void k_wvt(const float* __restrict__ Wv,
                                             u16* __restrict__ wvT) {
  __shared__ float tile[16][17];
  int tx = threadIdx.x & 15, ty = threadIdx.x >> 4;
  int nb = blockIdx.x * 16, kb = blockIdx.y * 16;
  tile[ty][tx] = Wv[(size_t)(kb + ty) * D_ + nb + tx];
  __syncthreads();
  wvT[(size_t)(nb + ty) * D_ + kb + tx] = f2bf(tile[tx][ty]);
}

// ---------------- K1: cast x -> bf16 (optional) + per-batch partial sums ---
// grid (NCHUNK=128, B_), 192 thr; 32 tokens per block; NO atomics.
template <bool CONV>
__global__ __launch_bounds__(192) void k_conv_mean(const float* __restrict__ x,
                                                   u16* __restrict__ xb,
                                                   float* __restrict__ partials) {
  int b = blockIdx.y, tc = blockIdx.x, tid = threadIdx.x;
  const float4* xp = (const float4*)(x + (size_t)(b * T_ + tc * 32) * D_) + tid;
  ushort4* op = nullptr;
  if (CONV) op = ((ushort4*)(xb + (size_t)(b * T_ + tc * 32) * D_)) + tid;
  float s0 = 0, s1 = 0, s2 = 0, s3 = 0;
  int tbase = tc * 32;
#pragma unroll 4
  for (int tt = 0; tt < 32; ++tt) {
    float4 v = xp[(size_t)tt * 192];
    if (CONV) {
      ushort4 o;
      o.x = f2bf(v.x); o.y = f2bf(v.y); o.z = f2bf(v.z); o.w = f2bf(v.w);
      op[(size_t)tt * 192] = o;
    }
    if (tbase + tt < TREG) { s0 += v.x; s1 += v.y; s2 += v.z; s3 += v.w; }
  }
  float4 st; st.x = s0; st.y = s1; st.z = s2; st.w = s3;
  ((float4*)(partials + ((size_t)b * NCHUNK + tc) * D_))[tid] = st;
}

// ---------------- K2a: reduce partials -> mean; ssu = mean @ Wk + bk -------
__global__ __launch_bounds__(256) void k_ssu(const float* __restrict__ partials,
                                             const float* __restrict__ Wk,
                                             const float* __restrict__ bk,
                                             float* __restrict__ ssu) {
  int b = blockIdx.y, tid = threadIdx.x;
  int n = blockIdx.x * 256 + tid;
  __shared__ float mv[D_];
  for (int d = tid; d < D_; d += 256) {
    const float* p = partials + (size_t)b * NCHUNK * D_ + d;
    float s = 0;
#pragma unroll 8
    for (int c = 0; c < NCHUNK; ++c) s += p[(size_t)c * D_];
    mv[d] = s * (1.0f / TREG);
  }
  __syncthreads();
  float a = bk[n];
#pragma unroll 8
  for (int d = 0; d < D_; ++d) a += mv[d] * Wk[(size_t)d * NK + n];
  ssu[(size_t)b * NK + n] = a;
}

// ---------------- K2b: new_ss rows + qb; grid (NSS, B_) --------------------
__global__ __launch_bounds__(256) void k_nss(
    const float* __restrict__ x, const float* __restrict__ ssu,
    const float* __restrict__ Wss, const float* __restrict__ bss,
    const float* __restrict__ bq, float* __restrict__ out,
    float* __restrict__ nssf, u16* __restrict__ nssT, float* __restrict__ qb) {
  int s = blockIdx.x, b = blockIdx.y, tid = threadIdx.x;
  __shared__ float su[INNER_];
  __shared__ float qred[4];
  if (tid < INNER_) su[tid] = ssu[(size_t)b * NK + s * INNER_ + tid];
  __syncthreads();
  size_t xr = (size_t)(b * T_ + TREG + s) * D_;
  float a0 = x[xr + tid]       + bss[tid];
  float a1 = x[xr + tid + 256] + bss[tid + 256];
  float a2 = x[xr + tid + 512] + bss[tid + 512];
#pragma unroll 4
  for (int i = 0; i < INNER_; ++i) {
    float sv = su[i];
    const float* wr = Wss + (size_t)i * D_ + tid;
    a0 += sv * wr[0]; a1 += sv * wr[256]; a2 += sv * wr[512];
  }
  out[xr + tid] = a0; out[xr + tid + 256] = a1; out[xr + tid + 512] = a2;
  size_t nb = (size_t)(b * NSS + s) * D_;
  nssf[nb + tid] = a0; nssf[nb + tid + 256] = a1; nssf[nb + tid + 512] = a2;
  size_t tb = (size_t)b * D_;
  nssT[(tb + tid) * NSS + s] = f2bf(a0);
  nssT[(tb + tid + 256) * NSS + s] = f2bf(a1);
  nssT[(tb + tid + 512) * NSS + s] = f2bf(a2);
  float q = bq[tid] * a0 + bq[tid + 256] * a1 + bq[tid + 512] * a2;
#pragma unroll
  for (int o = 1; o < 64; o <<= 1) q += __shfl_xor(q, o, 64);
  if ((tid & 63) == 0) qred[tid >> 6] = q;
  __syncthreads();
  if (tid == 0) qb[b * NSS + s] = qred[0] + qred[1] + qred[2] + qred[3];
}

// ---------------- K2c: Wqs[b] = Wq @ new_ss[b]^T -> bf16 [b][8][768] -------
__global__ __launch_bounds__(256) void k_wqs(const float* __restrict__ Wq,
                                             const float* __restrict__ nssf,
                                             u16* __restrict__ wqsT) {
  __shared__ float nss[NSS * (D_ + 4)];
  int b = blockIdx.y, tid = threadIdx.x;
  int o = blockIdx.x * 256 + tid;
  int j = o >> 3, s = o & 7;
  for (int i = tid; i < NSS * D_; i += 256) {
    int s2 = i / D_, d2 = i - s2 * D_;
    nss[s2 * (D_ + 4) + d2] = nssf[(size_t)b * NSS * D_ + i];
  }
  __syncthreads();
  const float* wr = Wq + (size_t)j * D_;
  const float* nr = nss + s * (D_ + 4);
  float a = 0;
#pragma unroll 8
  for (int d = 0; d < D_; ++d) a += wr[d] * nr[d];
  wqsT[((size_t)b * NSS + s) * D_ + j] = f2bf(a);
}

// ---------------- K3: fused x_v GEMM + sim + softmax + upd + ReLU ----------
// Round-4: (1) T2 XOR chunk-swizzle (pre-swizzled GLOBAL source + swizzled
// ds_read; LDS dest stays linear for global_load_lds), kills the 8-way
// bank conflict of stride-64B b128 fragment reads (-> 2-way, free).
// (2) T3-minimum 2-phase double-buffer: stage k+1 before computing k; ONE
// __syncthreads per K-step (24 barriers vs 48). Loop unrolled x2 so buffer
// pointers are compile-time (no runtime-indexed arrays -> no scratch).
// (3) Wqs folded into B tile as rows 128..135 (staged per K-step, 512B)
// -> Ws buffer deleted; LDS = 2*(8KB A + 8.5KB B) = 33792B -> 4 blocks/CU.
template <bool ABF16>
__global__ __launch_bounds__(256, 4) void k_main(
    const u16* __restrict__ xb, const float* __restrict__ xf,
    const u16* __restrict__ wvT, const u16* __restrict__ wqsT,
    const u16* __restrict__ nssTg, const float* __restrict__ qb,
    const float* __restrict__ bv, float* __restrict__ out) {
  __shared__ uint4 ldsv[2112];                 // 33792 B
  u16* lds = (u16*)ldsv;
  u16* As0 = lds;                              // 128x32 bf16
  u16* Bs0 = lds + 4096;                       // 136x32 bf16 (rows 128-135 = Wqs)
  u16* As1 = lds + 8448;
  u16* Bs1 = lds + 12544;

  const int tid = threadIdx.x;
  // XCD-aware decode: g = xcd + 8*(pair*6 + nblk); pid = pair*8 + xcd.
  const int g = blockIdx.x;
  const int xcd = g & 7;
  const int li = g >> 3;            // 0..383
  const int nblk = li % 6;
  const int pair = li / 6;          // 0..63
  const int pid = pair * 8 + xcd;   // 0..511 unique (t,b)
  const int t0 = (pid & 31) * 128;
  const int b = pid >> 5;
  const int n0 = nblk * 128;

  const int wave = tid >> 6, lane = tid & 63;
  const int wy = wave >> 1, wx = wave & 1;
  const int lr = lane & 15, lq = lane >> 4;

  // staging decode: thread covers (row = tid>>2, chunk = tid&3) and row+64.
  // source chunk is XOR-swizzled; LDS dest stays linear (rule #21).
  const int ar = tid >> 2;                       // 0..63
  const int agc = (tid & 3) ^ ((ar >> 1) & 3);   // swizzled global chunk
  // fragment-read chunk offset (u16): lq ^ ((row>>1)&3), row==...+lr and
  // 64/16-multiples drop out mod 4 -> constant across mt/nt/qf.
  const int fch = (lq ^ ((lr >> 1) & 3)) * 8;

  const u16* Bg = wvT + (size_t)n0 * D_;
  const u16* Qg = wqsT + (size_t)b * NSS * D_;   // 8 rows x 768
  const int qs = tid >> 2;                       // tid<32: s row 0..7
  const int qgc = (tid & 3) ^ ((qs >> 1) & 3);

  const u16* Ag16 = ABF16 ? (xb + (size_t)(b * T_ + t0) * D_) : nullptr;
  const float* Agf = ABF16 ? nullptr : (xf + (size_t)(b * T_ + t0) * D_);

  f32x4 acc[4][4];
  f32x4 sacc[4];
#pragma unroll
  for (int i = 0; i < 4; ++i) {
    sacc[i] = f32x4{0.f, 0.f, 0.f, 0.f};
#pragma unroll
    for (int j = 0; j < 4; ++j) acc[i][j] = f32x4{0.f, 0.f, 0.f, 0.f};
  }

  auto STAGE = [&](u16* As, u16* Bs, int k0) {
    if constexpr (ABF16) {
      load16_lds(Ag16 + (size_t)ar * D_ + k0 + agc * 8, As + tid * 8);
      load16_lds(Ag16 + (size_t)(ar + 64) * D_ + k0 + agc * 8,
                 As + (tid + 256) * 8);
    } else {
      const float* p0 = Agf + (size_t)ar * D_ + k0 + agc * 8;
      const float* p1 = Agf + (size_t)(ar + 64) * D_ + k0 + agc * 8;
      float4 a0 = *(const float4*)p0, a1 = *(const float4*)(p0 + 4);
      float4 a2 = *(const float4*)p1, a3 = *(const float4*)(p1 + 4);
      ushort4 w0, w1, w2, w3;
      w0.x = f2bf(a0.x); w0.y = f2bf(a0.y); w0.z = f2bf(a0.z); w0.w = f2bf(a0.w);
      w1.x = f2bf(a1.x); w1.y = f2bf(a1.y); w1.z = f2bf(a1.z); w1.w = f2bf(a1.w);
      w2.x = f2bf(a2.x); w2.y = f2bf(a2.y); w2.z = f2bf(a2.z); w2.w = f2bf(a2.w);
      w3.x = f2bf(a3.x); w3.y = f2bf(a3.y); w3.z = f2bf(a3.z); w3.w = f2bf(a3.w);
      *(ushort4*)(As + tid * 8) = w0; *(ushort4*)(As + tid * 8 + 4) = w1;
      *(ushort4*)(As + (tid + 256) * 8) = w2;
      *(ushort4*)(As + (tid + 256) * 8 + 4) = w3;
    }
    load16_lds(Bg + (size_t)ar * D_ + k0 + agc * 8, Bs + tid * 8);
    load16_lds(Bg + (size_t)(ar + 64) * D_ + k0 + agc * 8, Bs + (tid + 256) * 8);
    if (tid < 32)
      load16_lds(Qg + (size_t)qs * D_ + k0 + qgc * 8, Bs + 4096 + tid * 8);
  };

  auto COMPUTE = [&](const u16* As, const u16* Bs) {
    bf16x8 af[4], bfr[4], qf;
#pragma unroll
    for (int mt = 0; mt < 4; ++mt)
      af[mt] = *(const bf16x8*)(As + (wy * 64 + mt * 16 + lr) * 32 + fch);
#pragma unroll
    for (int nt = 0; nt < 4; ++nt)
      bfr[nt] = *(const bf16x8*)(Bs + (wx * 64 + nt * 16 + lr) * 32 + fch);
    qf = *(const bf16x8*)(Bs + (128 + (lr & 7)) * 32 + fch);
#pragma unroll
    for (int mt = 0; mt < 4; ++mt) {
#pragma unroll
      for (int nt = 0; nt < 4; ++nt)
        acc[mt][nt] = __builtin_amdgcn_mfma_f32_16x16x32_bf16(
            af[mt], bfr[nt], acc[mt][nt], 0, 0, 0);
      sacc[mt] = __builtin_amdgcn_mfma_f32_16x16x32_bf16(
          af[mt], qf, sacc[mt], 0, 0, 0);
    }
  };

  // 2-phase double-buffered pipeline, one barrier per K-step.
  STAGE(As0, Bs0, 0);
  __syncthreads();
#pragma unroll 1
  for (int k0 = 0; k0 < D_; k0 += 64) {
    STAGE(As1, Bs1, k0 + 32);
    COMPUTE(As0, Bs0);
    __syncthreads();
    if (k0 + 64 < D_) STAGE(As0, Bs0, k0 + 64);
    COMPUTE(As1, Bs1);
    __syncthreads();
  }

  // ---- epilogue: overlay anb(128x32) on As0, nsl(128x32) on Bs0 ----------
  u16* anb = lds;
  u16* nsl = lds + 4096;
  {
    uint4 z; z.x = z.y = z.z = z.w = 0;
    if (tid < 128) {
      uint4 v = *(const uint4*)(nssTg + ((size_t)b * D_ + n0 + tid) * NSS);
      int sw = ((tid >> 1) & 3) * 8;   // swizzled home of global chunk 0
      *(uint4*)(nsl + tid * 32 + sw) = v;
      *(uint4*)(nsl + tid * 32 + (sw ^ 8)) = z;
      *(uint4*)(nsl + tid * 32 + (sw ^ 16)) = z;
      *(uint4*)(nsl + tid * 32 + (sw ^ 24)) = z;
    } else {
      int r = tid - 128;
      *(uint4*)(anb + r * 32) = z;
      *(uint4*)(anb + r * 32 + 8) = z;
      *(uint4*)(anb + r * 32 + 16) = z;
      *(uint4*)(anb + r * 32 + 24) = z;
    }
  }
  __syncthreads();

  const float scale = 0.03608439182435161f;  // 1/sqrt(768)
  const float qbias = (lr < 8) ? qb[b * NSS + lr] : 0.f;
#pragma unroll
  for (int mt = 0; mt < 4; ++mt) {
    f32x4 s4 = sacc[mt];
#pragma unroll
    for (int r = 0; r < 4; ++r) {
      float v = (lr < 8) ? (s4[r] + qbias) * scale : -1.0e30f;
      float mx = v;
      mx = fmaxf(mx, __shfl_xor(mx, 1, 16));
      mx = fmaxf(mx, __shfl_xor(mx, 2, 16));
      mx = fmaxf(mx, __shfl_xor(mx, 4, 16));
      float e = (lr < 8) ? __expf(v - mx) : 0.f;
      float sm = e;
      sm += __shfl_xor(sm, 1, 16);
      sm += __shfl_xor(sm, 2, 16);
      sm += __shfl_xor(sm, 4, 16);
      if (lr < 8) {
        float a = e / sm;
        int row = wy * 64 + mt * 16 + lq * 4 + r;
        anb[row * 32 + ((row >> 1) & 3) * 8 + lr] = f2bf(a);
      }
    }
  }
  __syncthreads();

  // upd = attn @ new_ss via K-padded MFMA, accumulate into x_v accs
  bf16x8 nf[4];
#pragma unroll
  for (int nt = 0; nt < 4; ++nt)
    nf[nt] = *(const bf16x8*)(nsl + (wx * 64 + nt * 16 + lr) * 32 + fch);
#pragma unroll
  for (int mt = 0; mt < 4; ++mt) {
    bf16x8 afr =
        *(const bf16x8*)(anb + (wy * 64 + mt * 16 + lr) * 32 + fch);
#pragma unroll
    for (int nt = 0; nt < 4; ++nt)
      acc[mt][nt] = __builtin_amdgcn_mfma_f32_16x16x32_bf16(
          afr, nf[nt], acc[mt][nt], 0, 0, 0);
  }

  float bvv[4];
#pragma unroll
  for (int nt = 0; nt < 4; ++nt) bvv[nt] = bv[n0 + wx * 64 + nt * 16 + lr];
#pragma unroll
  for (int mt = 0; mt < 4; ++mt) {
    int trow = wy * 64 + mt * 16 + lq * 4;
#pragma unroll
    for (int r = 0; r < 4; ++r) {
      int token = t0 + trow + r;
      if (token < TREG) {
        float* op = out + ((size_t)b * T_ + token) * D_ + n0 + wx * 64;
#pragma unroll
        for (int nt = 0; nt < 4; ++nt)
          op[nt * 16 + lr] = fmaxf(acc[mt][nt][r] + bvv[nt], 0.f);
      }
    }
  }
}

extern "C" void kernel_launch(void* const* d_in, const int* in_sizes, int n_in,
                              void* d_out, int out_size, void* d_ws, size_t ws_size,
                              hipStream_t stream) {
  (void)in_sizes; (void)n_in; (void)out_size;
  const float* x   = (const float*)d_in[0];
  const float* Wq  = (const float*)d_in[1];
  const float* bq  = (const float*)d_in[2];
  const float* Wk  = (const float*)d_in[3];
  const float* bk  = (const float*)d_in[4];
  const float* Wv  = (const float*)d_in[5];
  const float* bv  = (const float*)d_in[6];
  const float* Wss = (const float*)d_in[7];
  const float* bss = (const float*)d_in[8];
  float* out = (float*)d_out;

  const size_t SZ_XB   = (size_t)B_ * T_ * D_ * 2;        // 100663296
  const size_t SZ_WVT  = (size_t)D_ * D_ * 2;             // 1179648
  const size_t SZ_PART = (size_t)B_ * NCHUNK * D_ * 4;    // 6291456
  const size_t SZ_SSU  = (size_t)B_ * NK * 4;             // 98304
  const size_t SZ_NSSF = (size_t)B_ * NSS * D_ * 4;       // 393216
  const size_t SZ_NSST = (size_t)B_ * D_ * NSS * 2;       // 196608
  const size_t SZ_QB   = (size_t)B_ * NSS * 4;            // 512
  const size_t SZ_WQS  = (size_t)B_ * NSS * D_ * 2;       // 196608
  const size_t SMALL = SZ_WVT + SZ_PART + SZ_SSU + SZ_NSSF + SZ_NSST + SZ_QB + SZ_WQS;
  const size_t FULL = SZ_XB + SMALL;
  const bool big = ws_size >= FULL;

  char* ws = (char*)d_ws;
  size_t off = big ? SZ_XB : 0;
  u16*   xb    = (u16*)ws;
  u16*   wvT   = (u16*)(ws + off);   off += SZ_WVT;
  float* parts = (float*)(ws + off); off += SZ_PART;
  float* ssu   = (float*)(ws + off); off += SZ_SSU;
  float* nssf  = (float*)(ws + off); off += SZ_NSSF;
  u16*   nssT  = (u16*)(ws + off);   off += SZ_NSST;
  float* qbb   = (float*)(ws + off); off += SZ_QB;
  u16*   wqsT  = (u16*)(ws + off);   off += SZ_WQS;

  k_wvt<<<dim3(48, 48), 256, 0, stream>>>(Wv, wvT);
  if (big)
    k_conv_mean<true><<<dim3(NCHUNK, 16), 192, 0, stream>>>(x, xb, parts);
  else
    k_conv_mean<false><<<dim3(NCHUNK, 16), 192, 0, stream>>>(x, nullptr, parts);
  k_ssu<<<dim3(6, 16), 256, 0, stream>>>(parts, Wk, bk, ssu);
  k_nss<<<dim3(NSS, 16), 256, 0, stream>>>(x, ssu, Wss, bss, bq, out, nssf, nssT, qbb);
  k_wqs<<<dim3(24, 16), 256, 0, stream>>>(Wq, nssf, wqsT);
  if (big)
    k_main<true><<<3072, 256, 0, stream>>>(xb, x, wvT, wqsT, nssT, qbb, bv, out);
  else
    k_main<false><<<3072, 256, 0, stream>>>(nullptr, x, wvT, wqsT, nssT, qbb, bv, out);
}

// Round 2
// 601.946 us; speedup vs baseline: 1.0449x; 1.0449x over previous
//
#include <hip/hip_runtime.h>
#include <hip/hip_bf16.h>

#define B_ 16
#define T_ 4096
#define TREG 4088
#define D_ 768
#define NSS 8
#define INNER_ 192
#define NK 1536
#define NCHUNK 128

typedef unsigned int u32;
typedef unsigned short u16;
typedef __attribute__((ext_vector_type(8))) short bf16x8;
typedef __attribute__((ext_vector_type(4))) float f32x4;

__device__ __forceinline__ u16 f2bf(float f) {
  union { __hip_bfloat16 h; u16 u; } cv;
  cv.h = __float2bfloat16(f);
  return cv.u;
}

// async global->LDS, 16B per lane. LDS dest is wave-uniform base + lane*16.
__device__ __forceinline__ void load16_lds(const void* g, void* l) {
  __builtin_amdgcn_global_load_lds(
      (const __attribute__((address_space(1))) u32*)(unsigned long long)g,
      (__attribute__((address_space(3))) u32*)(u32)(unsigned long long)l,
      16, 0, 0);
}

// ---------------- K0: Wv (768x768, k-major) -> WvT bf16 (n-major) ----------
__global__ __launch_bounds__(256) void k_wvt(const float* __restrict__ Wv,
                                             u16* __restrict__ wvT) {
  __shared__ float tile[16][17];
  int tx = threadIdx.x & 15, ty = threadIdx.x >> 4;
  int nb = blockIdx.x * 16, kb = blockIdx.y * 16;
  tile[ty][tx] = Wv[(size_t)(kb + ty) * D_ + nb + tx];
  __syncthreads();
  wvT[(size_t)(nb + ty) * D_ + kb + tx] = f2bf(tile[tx][ty]);
}

// ---------------- K1: cast x -> bf16 (optional) + per-batch partial sums ---
// grid (NCHUNK=128, B_), 192 thr; 32 tokens per block; NO atomics.
template <bool CONV>
__global__ __launch_bounds__(192) void k_conv_mean(const float* __restrict__ x,
                                                   u16* __restrict__ xb,
                                                   float* __restrict__ partials) {
  int b = blockIdx.y, tc = blockIdx.x, tid = threadIdx.x;
  const float4* xp = (const float4*)(x + (size_t)(b * T_ + tc * 32) * D_) + tid;
  ushort4* op = nullptr;
  if (CONV) op = ((ushort4*)(xb + (size_t)(b * T_ + tc * 32) * D_)) + tid;
  float s0 = 0, s1 = 0, s2 = 0, s3 = 0;
  int tbase = tc * 32;
#pragma unroll 4
  for (int tt = 0; tt < 32; ++tt) {
    float4 v = xp[(size_t)tt * 192];
    if (CONV) {
      ushort4 o;
      o.x = f2bf(v.x); o.y = f2bf(v.y); o.z = f2bf(v.z); o.w = f2bf(v.w);
      op[(size_t)tt * 192] = o;
    }
    if (tbase + tt < TREG) { s0 += v.x; s1 += v.y; s2 += v.z; s3 += v.w; }
  }
  float4 st; st.x = s0; st.y = s1; st.z = s2; st.w = s3;
  ((float4*)(partials + ((size_t)b * NCHUNK + tc) * D_))[tid] = st;
}

// ---------------- K2a: reduce partials -> mean; ssu = mean @ Wk + bk -------
__global__ __launch_bounds__(256) void k_ssu(const float* __restrict__ partials,
                                             const float* __restrict__ Wk,
                                             const float* __restrict__ bk,
                                             float* __restrict__ ssu) {
  int b = blockIdx.y, tid = threadIdx.x;
  int n = blockIdx.x * 256 + tid;
  __shared__ float mv[D_];
  for (int d = tid; d < D_; d += 256) {
    const float* p = partials + (size_t)b * NCHUNK * D_ + d;
    float s = 0;
#pragma unroll 8
    for (int c = 0; c < NCHUNK; ++c) s += p[(size_t)c * D_];
    mv[d] = s * (1.0f / TREG);
  }
  __syncthreads();
  float a = bk[n];
#pragma unroll 8
  for (int d = 0; d < D_; ++d) a += mv[d] * Wk[(size_t)d * NK + n];
  ssu[(size_t)b * NK + n] = a;
}

// ---------------- K2b: new_ss rows + qb; grid (NSS, B_) --------------------
__global__ __launch_bounds__(256) void k_nss(
    const float* __restrict__ x, const float* __restrict__ ssu,
    const float* __restrict__ Wss, const float* __restrict__ bss,
    const float* __restrict__ bq, float* __restrict__ out,
    float* __restrict__ nssf, u16* __restrict__ nssT, float* __restrict__ qb) {
  int s = blockIdx.x, b = blockIdx.y, tid = threadIdx.x;
  __shared__ float su[INNER_];
  __shared__ float qred[4];
  if (tid < INNER_) su[tid] = ssu[(size_t)b * NK + s * INNER_ + tid];
  __syncthreads();
  size_t xr = (size_t)(b * T_ + TREG + s) * D_;
  float a0 = x[xr + tid]       + bss[tid];
  float a1 = x[xr + tid + 256] + bss[tid + 256];
  float a2 = x[xr + tid + 512] + bss[tid + 512];
#pragma unroll 4
  for (int i = 0; i < INNER_; ++i) {
    float sv = su[i];
    const float* wr = Wss + (size_t)i * D_ + tid;
    a0 += sv * wr[0]; a1 += sv * wr[256]; a2 += sv * wr[512];
  }
  out[xr + tid] = a0; out[xr + tid + 256] = a1; out[xr + tid + 512] = a2;
  size_t nb = (size_t)(b * NSS + s) * D_;
  nssf[nb + tid] = a0; nssf[nb + tid + 256] = a1; nssf[nb + tid + 512] = a2;
  size_t tb = (size_t)b * D_;
  nssT[(tb + tid) * NSS + s] = f2bf(a0);
  nssT[(tb + tid + 256) * NSS + s] = f2bf(a1);
  nssT[(tb + tid + 512) * NSS + s] = f2bf(a2);
  float q = bq[tid] * a0 + bq[tid + 256] * a1 + bq[tid + 512] * a2;
#pragma unroll
  for (int o = 1; o < 64; o <<= 1) q += __shfl_xor(q, o, 64);
  if ((tid & 63) == 0) qred[tid >> 6] = q;
  __syncthreads();
  if (tid == 0) qb[b * NSS + s] = qred[0] + qred[1] + qred[2] + qred[3];
}

// ---------------- K2c: Wqs[b] = Wq @ new_ss[b]^T -> bf16 [b][8][768] -------
__global__ __launch_bounds__(256) void k_wqs(const float* __restrict__ Wq,
                                             const float* __restrict__ nssf,
                                             u16* __restrict__ wqsT) {
  __shared__ float nss[NSS * (D_ + 4)];
  int b = blockIdx.y, tid = threadIdx.x;
  int o = blockIdx.x * 256 + tid;
  int j = o >> 3, s = o & 7;
  for (int i = tid; i < NSS * D_; i += 256) {
    int s2 = i / D_, d2 = i - s2 * D_;
    nss[s2 * (D_ + 4) + d2] = nssf[(size_t)b * NSS * D_ + i];
  }
  __syncthreads();
  const float* wr = Wq + (size_t)j * D_;
  const float* nr = nss + s * (D_ + 4);
  float a = 0;
#pragma unroll 8
  for (int d = 0; d < D_; ++d) a += wr[d] * nr[d];
  wqsT[((size_t)b * NSS + s) * D_ + j] = f2bf(a);
}

// ---------------- K3: fused x_v GEMM + sim + softmax + upd + ReLU ----------
// Round-5: round-4's T2 XOR chunk-swizzle (bank conflicts 1.24e7 -> 5.9e5,
// verified) + 2-phase double-buffer (one barrier/K-step) RETAINED; the
// round-4 regression was __launch_bounds__(256,4) capping the unified
// register file at 128/thread -> spill (arch VGPR 76->64, WRITE_SIZE
// +83 MB of scratch traffic). Revert ONLY that: (256,3) gives the 170-reg
// budget that round 0 proved spill-free (80 acc + 36 frag + addressing).
template <bool ABF16>
__global__ __launch_bounds__(256, 3) void k_main(
    const u16* __restrict__ xb, const float* __restrict__ xf,
    const u16* __restrict__ wvT, const u16* __restrict__ wqsT,
    const u16* __restrict__ nssTg, const float* __restrict__ qb,
    const float* __restrict__ bv, float* __restrict__ out) {
  __shared__ uint4 ldsv[2112];                 // 33792 B
  u16* lds = (u16*)ldsv;
  u16* As0 = lds;                              // 128x32 bf16
  u16* Bs0 = lds + 4096;                       // 136x32 bf16 (rows 128-135 = Wqs)
  u16* As1 = lds + 8448;
  u16* Bs1 = lds + 12544;

  const int tid = threadIdx.x;
  // XCD-aware decode: g = xcd + 8*(pair*6 + nblk); pid = pair*8 + xcd.
  const int g = blockIdx.x;
  const int xcd = g & 7;
  const int li = g >> 3;            // 0..383
  const int nblk = li % 6;
  const int pair = li / 6;          // 0..63
  const int pid = pair * 8 + xcd;   // 0..511 unique (t,b)
  const int t0 = (pid & 31) * 128;
  const int b = pid >> 5;
  const int n0 = nblk * 128;

  const int wave = tid >> 6, lane = tid & 63;
  const int wy = wave >> 1, wx = wave & 1;
  const int lr = lane & 15, lq = lane >> 4;

  // staging decode: thread covers (row = tid>>2, chunk = tid&3) and row+64.
  // source chunk is XOR-swizzled; LDS dest stays linear (rule #21).
  const int ar = tid >> 2;                       // 0..63
  const int agc = (tid & 3) ^ ((ar >> 1) & 3);   // swizzled global chunk
  // fragment-read chunk offset (u16): lq ^ ((row>>1)&3), row==...+lr and
  // 64/16-multiples drop out mod 4 -> constant across mt/nt/qf.
  const int fch = (lq ^ ((lr >> 1) & 3)) * 8;

  const u16* Bg = wvT + (size_t)n0 * D_;
  const u16* Qg = wqsT + (size_t)b * NSS * D_;   // 8 rows x 768
  const int qs = tid >> 2;                       // tid<32: s row 0..7
  const int qgc = (tid & 3) ^ ((qs >> 1) & 3);

  const u16* Ag16 = ABF16 ? (xb + (size_t)(b * T_ + t0) * D_) : nullptr;
  const float* Agf = ABF16 ? nullptr : (xf + (size_t)(b * T_ + t0) * D_);

  f32x4 acc[4][4];
  f32x4 sacc[4];
#pragma unroll
  for (int i = 0; i < 4; ++i) {
    sacc[i] = f32x4{0.f, 0.f, 0.f, 0.f};
#pragma unroll
    for (int j = 0; j < 4; ++j) acc[i][j] = f32x4{0.f, 0.f, 0.f, 0.f};
  }

  auto STAGE = [&](u16* As, u16* Bs, int k0) {
    if constexpr (ABF16) {
      load16_lds(Ag16 + (size_t)ar * D_ + k0 + agc * 8, As + tid * 8);
      load16_lds(Ag16 + (size_t)(ar + 64) * D_ + k0 + agc * 8,
                 As + (tid + 256) * 8);
    } else {
      const float* p0 = Agf + (size_t)ar * D_ + k0 + agc * 8;
      const float* p1 = Agf + (size_t)(ar + 64) * D_ + k0 + agc * 8;
      float4 a0 = *(const float4*)p0, a1 = *(const float4*)(p0 + 4);
      float4 a2 = *(const float4*)p1, a3 = *(const float4*)(p1 + 4);
      ushort4 w0, w1, w2, w3;
      w0.x = f2bf(a0.x); w0.y = f2bf(a0.y); w0.z = f2bf(a0.z); w0.w = f2bf(a0.w);
      w1.x = f2bf(a1.x); w1.y = f2bf(a1.y); w1.z = f2bf(a1.z); w1.w = f2bf(a1.w);
      w2.x = f2bf(a2.x); w2.y = f2bf(a2.y); w2.z = f2bf(a2.z); w2.w = f2bf(a2.w);
      w3.x = f2bf(a3.x); w3.y = f2bf(a3.y); w3.z = f2bf(a3.z); w3.w = f2bf(a3.w);
      *(ushort4*)(As + tid * 8) = w0; *(ushort4*)(As + tid * 8 + 4) = w1;
      *(ushort4*)(As + (tid + 256) * 8) = w2;
      *(ushort4*)(As + (tid + 256) * 8 + 4) = w3;
    }
    load16_lds(Bg + (size_t)ar * D_ + k0 + agc * 8, Bs + tid * 8);
    load16_lds(Bg + (size_t)(ar + 64) * D_ + k0 + agc * 8, Bs + (tid + 256) * 8);
    if (tid < 32)
      load16_lds(Qg + (size_t)qs * D_ + k0 + qgc * 8, Bs + 4096 + tid * 8);
  };

  auto COMPUTE = [&](const u16* As, const u16* Bs) {
    bf16x8 af[4], bfr[4], qf;
#pragma unroll
    for (int mt = 0; mt < 4; ++mt)
      af[mt] = *(const bf16x8*)(As + (wy * 64 + mt * 16 + lr) * 32 + fch);
#pragma unroll
    for (int nt = 0; nt < 4; ++nt)
      bfr[nt] = *(const bf16x8*)(Bs + (wx * 64 + nt * 16 + lr) * 32 + fch);
    qf = *(const bf16x8*)(Bs + (128 + (lr & 7)) * 32 + fch);
#pragma unroll
    for (int mt = 0; mt < 4; ++mt) {
#pragma unroll
      for (int nt = 0; nt < 4; ++nt)
        acc[mt][nt] = __builtin_amdgcn_mfma_f32_16x16x32_bf16(
            af[mt], bfr[nt], acc[mt][nt], 0, 0, 0);
      sacc[mt] = __builtin_amdgcn_mfma_f32_16x16x32_bf16(
          af[mt], qf, sacc[mt], 0, 0, 0);
    }
  };

  // 2-phase double-buffered pipeline, one barrier per K-step.
  STAGE(As0, Bs0, 0);
  __syncthreads();
#pragma unroll 1
  for (int k0 = 0; k0 < D_; k0 += 64) {
    STAGE(As1, Bs1, k0 + 32);
    COMPUTE(As0, Bs0);
    __syncthreads();
    if (k0 + 64 < D_) STAGE(As0, Bs0, k0 + 64);
    COMPUTE(As1, Bs1);
    __syncthreads();
  }

  // ---- epilogue: overlay anb(128x32) on As0, nsl(128x32) on Bs0 ----------
  u16* anb = lds;
  u16* nsl = lds + 4096;
  {
    uint4 z; z.x = z.y = z.z = z.w = 0;
    if (tid < 128) {
      uint4 v = *(const uint4*)(nssTg + ((size_t)b * D_ + n0 + tid) * NSS);
      int sw = ((tid >> 1) & 3) * 8;   // swizzled home of global chunk 0
      *(uint4*)(nsl + tid * 32 + sw) = v;
      *(uint4*)(nsl + tid * 32 + (sw ^ 8)) = z;
      *(uint4*)(nsl + tid * 32 + (sw ^ 16)) = z;
      *(uint4*)(nsl + tid * 32 + (sw ^ 24)) = z;
    } else {
      int r = tid - 128;
      *(uint4*)(anb + r * 32) = z;
      *(uint4*)(anb + r * 32 + 8) = z;
      *(uint4*)(anb + r * 32 + 16) = z;
      *(uint4*)(anb + r * 32 + 24) = z;
    }
  }
  __syncthreads();

  const float scale = 0.03608439182435161f;  // 1/sqrt(768)
  const float qbias = (lr < 8) ? qb[b * NSS + lr] : 0.f;
#pragma unroll
  for (int mt = 0; mt < 4; ++mt) {
    f32x4 s4 = sacc[mt];
#pragma unroll
    for (int r = 0; r < 4; ++r) {
      float v = (lr < 8) ? (s4[r] + qbias) * scale : -1.0e30f;
      float mx = v;
      mx = fmaxf(mx, __shfl_xor(mx, 1, 16));
      mx = fmaxf(mx, __shfl_xor(mx, 2, 16));
      mx = fmaxf(mx, __shfl_xor(mx, 4, 16));
      float e = (lr < 8) ? __expf(v - mx) : 0.f;
      float sm = e;
      sm += __shfl_xor(sm, 1, 16);
      sm += __shfl_xor(sm, 2, 16);
      sm += __shfl_xor(sm, 4, 16);
      if (lr < 8) {
        float a = e / sm;
        int row = wy * 64 + mt * 16 + lq * 4 + r;
        anb[row * 32 + ((row >> 1) & 3) * 8 + lr] = f2bf(a);
      }
    }
  }
  __syncthreads();

  // upd = attn @ new_ss via K-padded MFMA, accumulate into x_v accs
  bf16x8 nf[4];
#pragma unroll
  for (int nt = 0; nt < 4; ++nt)
    nf[nt] = *(const bf16x8*)(nsl + (wx * 64 + nt * 16 + lr) * 32 + fch);
#pragma unroll
  for (int mt = 0; mt < 4; ++mt) {
    bf16x8 afr =
        *(const bf16x8*)(anb + (wy * 64 + mt * 16 + lr) * 32 + fch);
#pragma unroll
    for (int nt = 0; nt < 4; ++nt)
      acc[mt][nt] = __builtin_amdgcn_mfma_f32_16x16x32_bf16(
          afr, nf[nt], acc[mt][nt], 0, 0, 0);
  }

  float bvv[4];
#pragma unroll
  for (int nt = 0; nt < 4; ++nt) bvv[nt] = bv[n0 + wx * 64 + nt * 16 + lr];
#pragma unroll
  for (int mt = 0; mt < 4; ++mt) {
    int trow = wy * 64 + mt * 16 + lq * 4;
#pragma unroll
    for (int r = 0; r < 4; ++r) {
      int token = t0 + trow + r;
      if (token < TREG) {
        float* op = out + ((size_t)b * T_ + token) * D_ + n0 + wx * 64;
#pragma unroll
        for (int nt = 0; nt < 4; ++nt)
          op[nt * 16 + lr] = fmaxf(acc[mt][nt][r] + bvv[nt], 0.f);
      }
    }
  }
}

extern "C" void kernel_launch(void* const* d_in, const int* in_sizes, int n_in,
                              void* d_out, int out_size, void* d_ws, size_t ws_size,
                              hipStream_t stream) {
  (void)in_sizes; (void)n_in; (void)out_size;
  const float* x   = (const float*)d_in[0];
  const float* Wq  = (const float*)d_in[1];
  const float* bq  = (const float*)d_in[2];
  const float* Wk  = (const float*)d_in[3];
  const float* bk  = (const float*)d_in[4];
  const float* Wv  = (const float*)d_in[5];
  const float* bv  = (const float*)d_in[6];
  const float* Wss = (const float*)d_in[7];
  const float* bss = (const float*)d_in[8];
  float* out = (float*)d_out;

  const size_t SZ_XB   = (size_t)B_ * T_ * D_ * 2;        // 100663296
  const size_t SZ_WVT  = (size_t)D_ * D_ * 2;             // 1179648
  const size_t SZ_PART = (size_t)B_ * NCHUNK * D_ * 4;    // 6291456
  const size_t SZ_SSU  = (size_t)B_ * NK * 4;             // 98304
  const size_t SZ_NSSF = (size_t)B_ * NSS * D_ * 4;       // 393216
  const size_t SZ_NSST = (size_t)B_ * D_ * NSS * 2;       // 196608
  const size_t SZ_QB   = (size_t)B_ * NSS * 4;            // 512
  const size_t SZ_WQS  = (size_t)B_ * NSS * D_ * 2;       // 196608
  const size_t SMALL = SZ_WVT + SZ_PART + SZ_SSU + SZ_NSSF + SZ_NSST + SZ_QB + SZ_WQS;
  const size_t FULL = SZ_XB + SMALL;
  const bool big = ws_size >= FULL;

  char* ws = (char*)d_ws;
  size_t off = big ? SZ_XB : 0;
  u16*   xb    = (u16*)ws;
  u16*   wvT   = (u16*)(ws + off);   off += SZ_WVT;
  float* parts = (float*)(ws + off); off += SZ_PART;
  float* ssu   = (float*)(ws + off); off += SZ_SSU;
  float* nssf  = (float*)(ws + off); off += SZ_NSSF;
  u16*   nssT  = (u16*)(ws + off);   off += SZ_NSST;
  float* qbb   = (float*)(ws + off); off += SZ_QB;
  u16*   wqsT  = (u16*)(ws + off);   off += SZ_WQS;

  k_wvt<<<dim3(48, 48), 256, 0, stream>>>(Wv, wvT);
  if (big)
    k_conv_mean<true><<<dim3(NCHUNK, 16), 192, 0, stream>>>(x, xb, parts);
  else
    k_conv_mean<false><<<dim3(NCHUNK, 16), 192, 0, stream>>>(x, nullptr, parts);
  k_ssu<<<dim3(6, 16), 256, 0, stream>>>(parts, Wk, bk, ssu);
  k_nss<<<dim3(NSS, 16), 256, 0, stream>>>(x, ssu, Wss, bss, bq, out, nssf, nssT, qbb);
  k_wqs<<<dim3(24, 16), 256, 0, stream>>>(Wq, nssf, wqsT);
  if (big)
    k_main<true><<<3072, 256, 0, stream>>>(xb, x, wvT, wqsT, nssT, qbb, bv, out);
  else
    k_main<false><<<3072, 256, 0, stream>>>(nullptr, x, wvT, wqsT, nssT, qbb, bv, out);
}

// Round 4
// 597.989 us; speedup vs baseline: 1.0518x; 1.0066x over previous
//
#include <hip/hip_runtime.h>
#include <hip/hip_bf16.h>

#define B_ 16
#define T_ 4096
#define TREG 4088
#define D_ 768
#define NSS 8
#define INNER_ 192
#define NK 1536
#define NCHUNK 128

typedef unsigned int u32;
typedef unsigned short u16;
typedef __attribute__((ext_vector_type(8))) short bf16x8;
typedef __attribute__((ext_vector_type(4))) float f32x4;

__device__ __forceinline__ u16 f2bf(float f) {
  union { __hip_bfloat16 h; u16 u; } cv;
  cv.h = __float2bfloat16(f);
  return cv.u;
}

// async global->LDS, 16B per lane. LDS dest is wave-uniform base + lane*16.
__device__ __forceinline__ void load16_lds(const void* g, void* l) {
  __builtin_amdgcn_global_load_lds(
      (const __attribute__((address_space(1))) u32*)(unsigned long long)g,
      (__attribute__((address_space(3))) u32*)(u32)(unsigned long long)l,
      16, 0, 0);
}

// ---------------- K0: Wv (768x768, k-major) -> WvT bf16 (n-major) ----------
__global__ __launch_bounds__(256) void k_wvt(const float* __restrict__ Wv,
                                             u16* __restrict__ wvT) {
  __shared__ float tile[16][17];
  int tx = threadIdx.x & 15, ty = threadIdx.x >> 4;
  int nb = blockIdx.x * 16, kb = blockIdx.y * 16;
  tile[ty][tx] = Wv[(size_t)(kb + ty) * D_ + nb + tx];
  __syncthreads();
  wvT[(size_t)(nb + ty) * D_ + kb + tx] = f2bf(tile[tx][ty]);
}

// ---------------- K1: cast x -> bf16 (optional) + per-batch partial sums ---
// grid (NCHUNK=128, B_), 192 thr; 32 tokens per block; NO atomics.
template <bool CONV>
__global__ __launch_bounds__(192) void k_conv_mean(const float* __restrict__ x,
                                                   u16* __restrict__ xb,
                                                   float* __restrict__ partials) {
  int b = blockIdx.y, tc = blockIdx.x, tid = threadIdx.x;
  const float4* xp = (const float4*)(x + (size_t)(b * T_ + tc * 32) * D_) + tid;
  ushort4* op = nullptr;
  if (CONV) op = ((ushort4*)(xb + (size_t)(b * T_ + tc * 32) * D_)) + tid;
  float s0 = 0, s1 = 0, s2 = 0, s3 = 0;
  int tbase = tc * 32;
#pragma unroll 4
  for (int tt = 0; tt < 32; ++tt) {
    float4 v = xp[(size_t)tt * 192];
    if (CONV) {
      ushort4 o;
      o.x = f2bf(v.x); o.y = f2bf(v.y); o.z = f2bf(v.z); o.w = f2bf(v.w);
      op[(size_t)tt * 192] = o;
    }
    if (tbase + tt < TREG) { s0 += v.x; s1 += v.y; s2 += v.z; s3 += v.w; }
  }
  float4 st; st.x = s0; st.y = s1; st.z = s2; st.w = s3;
  ((float4*)(partials + ((size_t)b * NCHUNK + tc) * D_))[tid] = st;
}

// ---------------- K2a: reduce partials -> mean; ssu = mean @ Wk + bk -------
__global__ __launch_bounds__(256) void k_ssu(const float* __restrict__ partials,
                                             const float* __restrict__ Wk,
                                             const float* __restrict__ bk,
                                             float* __restrict__ ssu) {
  int b = blockIdx.y, tid = threadIdx.x;
  int n = blockIdx.x * 256 + tid;
  __shared__ float mv[D_];
  for (int d = tid; d < D_; d += 256) {
    const float* p = partials + (size_t)b * NCHUNK * D_ + d;
    float s = 0;
#pragma unroll 8
    for (int c = 0; c < NCHUNK; ++c) s += p[(size_t)c * D_];
    mv[d] = s * (1.0f / TREG);
  }
  __syncthreads();
  float a = bk[n];
#pragma unroll 8
  for (int d = 0; d < D_; ++d) a += mv[d] * Wk[(size_t)d * NK + n];
  ssu[(size_t)b * NK + n] = a;
}

// ---------------- K2b: new_ss rows + qb; grid (NSS, B_) --------------------
__global__ __launch_bounds__(256) void k_nss(
    const float* __restrict__ x, const float* __restrict__ ssu,
    const float* __restrict__ Wss, const float* __restrict__ bss,
    const float* __restrict__ bq, float* __restrict__ out,
    float* __restrict__ nssf, u16* __restrict__ nssT, float* __restrict__ qb) {
  int s = blockIdx.x, b = blockIdx.y, tid = threadIdx.x;
  __shared__ float su[INNER_];
  __shared__ float qred[4];
  if (tid < INNER_) su[tid] = ssu[(size_t)b * NK + s * INNER_ + tid];
  __syncthreads();
  size_t xr = (size_t)(b * T_ + TREG + s) * D_;
  float a0 = x[xr + tid]       + bss[tid];
  float a1 = x[xr + tid + 256] + bss[tid + 256];
  float a2 = x[xr + tid + 512] + bss[tid + 512];
#pragma unroll 4
  for (int i = 0; i < INNER_; ++i) {
    float sv = su[i];
    const float* wr = Wss + (size_t)i * D_ + tid;
    a0 += sv * wr[0]; a1 += sv * wr[256]; a2 += sv * wr[512];
  }
  out[xr + tid] = a0; out[xr + tid + 256] = a1; out[xr + tid + 512] = a2;
  size_t nb = (size_t)(b * NSS + s) * D_;
  nssf[nb + tid] = a0; nssf[nb + tid + 256] = a1; nssf[nb + tid + 512] = a2;
  size_t tb = (size_t)b * D_;
  nssT[(tb + tid) * NSS + s] = f2bf(a0);
  nssT[(tb + tid + 256) * NSS + s] = f2bf(a1);
  nssT[(tb + tid + 512) * NSS + s] = f2bf(a2);
  float q = bq[tid] * a0 + bq[tid + 256] * a1 + bq[tid + 512] * a2;
#pragma unroll
  for (int o = 1; o < 64; o <<= 1) q += __shfl_xor(q, o, 64);
  if ((tid & 63) == 0) qred[tid >> 6] = q;
  __syncthreads();
  if (tid == 0) qb[b * NSS + s] = qred[0] + qred[1] + qred[2] + qred[3];
}

// ---------------- K2c: Wqs[b] = Wq @ new_ss[b]^T -> bf16 [b][8][768] -------
__global__ __launch_bounds__(256) void k_wqs(const float* __restrict__ Wq,
                                             const float* __restrict__ nssf,
                                             u16* __restrict__ wqsT) {
  __shared__ float nss[NSS * (D_ + 4)];
  int b = blockIdx.y, tid = threadIdx.x;
  int o = blockIdx.x * 256 + tid;
  int j = o >> 3, s = o & 7;
  for (int i = tid; i < NSS * D_; i += 256) {
    int s2 = i / D_, d2 = i - s2 * D_;
    nss[s2 * (D_ + 4) + d2] = nssf[(size_t)b * NSS * D_ + i];
  }
  __syncthreads();
  const float* wr = Wq + (size_t)j * D_;
  const float* nr = nss + s * (D_ + 4);
  float a = 0;
#pragma unroll 8
  for (int d = 0; d < D_; ++d) a += wr[d] * nr[d];
  wqsT[((size_t)b * NSS + s) * D_ + j] = f2bf(a);
}

// ---------------- K3: fused x_v GEMM + sim + softmax + upd + ReLU ----------
// Round-7 == round-6 resubmit (container failed twice; source audited clean:
// no barrier divergence, vmcnt wave-uniform 5/stage, no OOB, WAR-safe).
// Design: T3+T4 — 3-buffer depth-2 prefetch with COUNTED vmcnt(5) + raw
// s_barrier (never drain to 0 in the loop). Stage(s) is consumed at step
// s+2: two compute phases + two barriers of cover for ~500-900cy load
// latency. Q-row staging redistributed (1 load16_lds per wave) so every
// wave issues exactly 5 VMEM ops per stage -> wave-uniform vmcnt counting.
// lgkmcnt(0) before each barrier guarantees LDS reads drained before any
// wave can overwrite a retired buffer (WAR safety).
template <bool ABF16>
__global__ __launch_bounds__(256, 3) void k_main(
    const u16* __restrict__ xb, const float* __restrict__ xf,
    const u16* __restrict__ wvT, const u16* __restrict__ wqsT,
    const u16* __restrict__ nssTg, const float* __restrict__ qb,
    const float* __restrict__ bv, float* __restrict__ out) {
  __shared__ uint4 ldsv[3168];                 // 50688 B = 3 x (8KB A + 8.5KB B)
  u16* lds = (u16*)ldsv;
  u16* As0 = lds;          u16* Bs0 = lds + 4096;
  u16* As1 = lds + 8448;   u16* Bs1 = lds + 12544;
  u16* As2 = lds + 16896;  u16* Bs2 = lds + 20992;

  const int tid = threadIdx.x;
  // XCD-aware decode: g = xcd + 8*(pair*6 + nblk); pid = pair*8 + xcd.
  const int g = blockIdx.x;
  const int xcd = g & 7;
  const int li = g >> 3;            // 0..383
  const int nblk = li % 6;
  const int pair = li / 6;          // 0..63
  const int pid = pair * 8 + xcd;   // 0..511 unique (t,b)
  const int t0 = (pid & 31) * 128;
  const int b = pid >> 5;
  const int n0 = nblk * 128;

  const int wave = tid >> 6, lane = tid & 63;
  const int wy = wave >> 1, wx = wave & 1;
  const int lr = lane & 15, lq = lane >> 4;

  // staging decode: thread covers (row = tid>>2, chunk = tid&3) and row+64.
  // source chunk is XOR-swizzled; LDS dest stays linear (rule #21).
  const int ar = tid >> 2;                       // 0..63
  const int agc = (tid & 3) ^ ((ar >> 1) & 3);   // swizzled global chunk
  // fragment-read chunk offset (u16): lq ^ ((row>>1)&3); row components that
  // are multiples of 4 drop out -> constant across mt/nt/qf.
  const int fch = (lq ^ ((lr >> 1) & 3)) * 8;

  const u16* Bg = wvT + (size_t)n0 * D_;
  const u16* Qg = wqsT + (size_t)b * NSS * D_;   // 8 rows x 768
  // Q staging: wave w, lanes 0..7 load rows 2w,2w+1 (1 instr per wave ->
  // uniform vmcnt). global chunk = (lane&3) ^ ((qrow>>1)&3) = (lane&3)^wave.
  const int qrow = 2 * wave + ((lane >> 2) & 1);
  const int qc = (lane & 3) ^ wave;

  const u16* Ag16 = ABF16 ? (xb + (size_t)(b * T_ + t0) * D_) : nullptr;
  const float* Agf = ABF16 ? nullptr : (xf + (size_t)(b * T_ + t0) * D_);

  f32x4 acc[4][4];
  f32x4 sacc[4];
#pragma unroll
  for (int i = 0; i < 4; ++i) {
    sacc[i] = f32x4{0.f, 0.f, 0.f, 0.f};
#pragma unroll
    for (int j = 0; j < 4; ++j) acc[i][j] = f32x4{0.f, 0.f, 0.f, 0.f};
  }

  auto STAGE = [&](u16* As, u16* Bs, int k0) {
    if constexpr (ABF16) {
      load16_lds(Ag16 + (size_t)ar * D_ + k0 + agc * 8, As + tid * 8);
      load16_lds(Ag16 + (size_t)(ar + 64) * D_ + k0 + agc * 8,
                 As + (tid + 256) * 8);
    } else {
      const float* p0 = Agf + (size_t)ar * D_ + k0 + agc * 8;
      const float* p1 = Agf + (size_t)(ar + 64) * D_ + k0 + agc * 8;
      float4 a0 = *(const float4*)p0, a1 = *(const float4*)(p0 + 4);
      float4 a2 = *(const float4*)p1, a3 = *(const float4*)(p1 + 4);
      ushort4 w0, w1, w2, w3;
      w0.x = f2bf(a0.x); w0.y = f2bf(a0.y); w0.z = f2bf(a0.z); w0.w = f2bf(a0.w);
      w1.x = f2bf(a1.x); w1.y = f2bf(a1.y); w1.z = f2bf(a1.z); w1.w = f2bf(a1.w);
      w2.x = f2bf(a2.x); w2.y = f2bf(a2.y); w2.z = f2bf(a2.z); w2.w = f2bf(a2.w);
      w3.x = f2bf(a3.x); w3.y = f2bf(a3.y); w3.z = f2bf(a3.z); w3.w = f2bf(a3.w);
      *(ushort4*)(As + tid * 8) = w0; *(ushort4*)(As + tid * 8 + 4) = w1;
      *(ushort4*)(As + (tid + 256) * 8) = w2;
      *(ushort4*)(As + (tid + 256) * 8 + 4) = w3;
    }
    load16_lds(Bg + (size_t)ar * D_ + k0 + agc * 8, Bs + tid * 8);
    load16_lds(Bg + (size_t)(ar + 64) * D_ + k0 + agc * 8, Bs + (tid + 256) * 8);
    if (lane < 8)
      load16_lds(Qg + (size_t)qrow * D_ + k0 + qc * 8,
                 Bs + 4096 + wave * 64 + lane * 8);
  };

  auto COMPUTE = [&](const u16* As, const u16* Bs) {
    bf16x8 af[4], bfr[4], qf;
#pragma unroll
    for (int mt = 0; mt < 4; ++mt)
      af[mt] = *(const bf16x8*)(As + (wy * 64 + mt * 16 + lr) * 32 + fch);
#pragma unroll
    for (int nt = 0; nt < 4; ++nt)
      bfr[nt] = *(const bf16x8*)(Bs + (wx * 64 + nt * 16 + lr) * 32 + fch);
    qf = *(const bf16x8*)(Bs + (128 + (lr & 7)) * 32 + fch);
#pragma unroll
    for (int mt = 0; mt < 4; ++mt) {
#pragma unroll
      for (int nt = 0; nt < 4; ++nt)
        acc[mt][nt] = __builtin_amdgcn_mfma_f32_16x16x32_bf16(
            af[mt], bfr[nt], acc[mt][nt], 0, 0, 0);
      sacc[mt] = __builtin_amdgcn_mfma_f32_16x16x32_bf16(
          af[mt], qf, sacc[mt], 0, 0, 0);
    }
  };

  // Counted-vmcnt waits: retire only the OLDEST stage (5 VMEM/wave); the
  // newer one stays in flight across the barrier. lgkmcnt(0) = WAR safety.
  auto WAIT5 = [&]() {
    asm volatile("s_waitcnt vmcnt(5) lgkmcnt(0)" ::: "memory");
    __builtin_amdgcn_s_barrier();
    __builtin_amdgcn_sched_barrier(0);
  };
  auto WAIT0 = [&]() {
    asm volatile("s_waitcnt vmcnt(0) lgkmcnt(0)" ::: "memory");
    __builtin_amdgcn_s_barrier();
    __builtin_amdgcn_sched_barrier(0);
  };

  if constexpr (ABF16) {
    // 24 K-steps of 32; stage(s) consumed at step s+2 (depth-2 pipeline).
    STAGE(As0, Bs0, 0);
    STAGE(As1, Bs1, 32);
    int kk = 0;
#pragma unroll 1
    for (int it = 0; it < 7; ++it, kk += 96) {
      WAIT5(); STAGE(As2, Bs2, kk + 64);  COMPUTE(As0, Bs0);
      WAIT5(); STAGE(As0, Bs0, kk + 96);  COMPUTE(As1, Bs1);
      WAIT5(); STAGE(As1, Bs1, kk + 128); COMPUTE(As2, Bs2);
    }
    // tail: s = 21, 22, 23 (kk == 672)
    WAIT5(); STAGE(As2, Bs2, 736); COMPUTE(As0, Bs0);  // data 672
    WAIT5(); COMPUTE(As1, Bs1);                        // data 704
    WAIT0(); COMPUTE(As2, Bs2);                        // data 736
  } else {
    // fallback float path: round-2 structure (2 buffers, __syncthreads).
    STAGE(As0, Bs0, 0);
    __syncthreads();
#pragma unroll 1
    for (int k0 = 0; k0 < D_; k0 += 64) {
      STAGE(As1, Bs1, k0 + 32);
      COMPUTE(As0, Bs0);
      __syncthreads();
      if (k0 + 64 < D_) STAGE(As0, Bs0, k0 + 64);
      COMPUTE(As1, Bs1);
      __syncthreads();
    }
  }

  // ---- epilogue: overlay anb(128x32) on As0, nsl(128x32) on Bs0 ----------
  // buf0's last reader was step 21; all waves passed the step-22 barrier
  // (lgkmcnt(0)-drained) before reaching here -> safe to overwrite.
  u16* anb = lds;
  u16* nsl = lds + 4096;
  {
    uint4 z; z.x = z.y = z.z = z.w = 0;
    if (tid < 128) {
      uint4 v = *(const uint4*)(nssTg + ((size_t)b * D_ + n0 + tid) * NSS);
      int sw = ((tid >> 1) & 3) * 8;   // swizzled home of global chunk 0
      *(uint4*)(nsl + tid * 32 + sw) = v;
      *(uint4*)(nsl + tid * 32 + (sw ^ 8)) = z;
      *(uint4*)(nsl + tid * 32 + (sw ^ 16)) = z;
      *(uint4*)(nsl + tid * 32 + (sw ^ 24)) = z;
    } else {
      int r = tid - 128;
      *(uint4*)(anb + r * 32) = z;
      *(uint4*)(anb + r * 32 + 8) = z;
      *(uint4*)(anb + r * 32 + 16) = z;
      *(uint4*)(anb + r * 32 + 24) = z;
    }
  }
  __syncthreads();

  const float scale = 0.03608439182435161f;  // 1/sqrt(768)
  const float qbias = (lr < 8) ? qb[b * NSS + lr] : 0.f;
#pragma unroll
  for (int mt = 0; mt < 4; ++mt) {
    f32x4 s4 = sacc[mt];
#pragma unroll
    for (int r = 0; r < 4; ++r) {
      float v = (lr < 8) ? (s4[r] + qbias) * scale : -1.0e30f;
      float mx = v;
      mx = fmaxf(mx, __shfl_xor(mx, 1, 16));
      mx = fmaxf(mx, __shfl_xor(mx, 2, 16));
      mx = fmaxf(mx, __shfl_xor(mx, 4, 16));
      float e = (lr < 8) ? __expf(v - mx) : 0.f;
      float sm = e;
      sm += __shfl_xor(sm, 1, 16);
      sm += __shfl_xor(sm, 2, 16);
      sm += __shfl_xor(sm, 4, 16);
      if (lr < 8) {
        float a = e / sm;
        int row = wy * 64 + mt * 16 + lq * 4 + r;
        anb[row * 32 + ((row >> 1) & 3) * 8 + lr] = f2bf(a);
      }
    }
  }
  __syncthreads();

  // upd = attn @ new_ss via K-padded MFMA, accumulate into x_v accs
  bf16x8 nf[4];
#pragma unroll
  for (int nt = 0; nt < 4; ++nt)
    nf[nt] = *(const bf16x8*)(nsl + (wx * 64 + nt * 16 + lr) * 32 + fch);
#pragma unroll
  for (int mt = 0; mt < 4; ++mt) {
    bf16x8 afr =
        *(const bf16x8*)(anb + (wy * 64 + mt * 16 + lr) * 32 + fch);
#pragma unroll
    for (int nt = 0; nt < 4; ++nt)
      acc[mt][nt] = __builtin_amdgcn_mfma_f32_16x16x32_bf16(
          afr, nf[nt], acc[mt][nt], 0, 0, 0);
  }

  float bvv[4];
#pragma unroll
  for (int nt = 0; nt < 4; ++nt) bvv[nt] = bv[n0 + wx * 64 + nt * 16 + lr];
#pragma unroll
  for (int mt = 0; mt < 4; ++mt) {
    int trow = wy * 64 + mt * 16 + lq * 4;
#pragma unroll
    for (int r = 0; r < 4; ++r) {
      int token = t0 + trow + r;
      if (token < TREG) {
        float* op = out + ((size_t)b * T_ + token) * D_ + n0 + wx * 64;
#pragma unroll
        for (int nt = 0; nt < 4; ++nt)
          op[nt * 16 + lr] = fmaxf(acc[mt][nt][r] + bvv[nt], 0.f);
      }
    }
  }
}

extern "C" void kernel_launch(void* const* d_in, const int* in_sizes, int n_in,
                              void* d_out, int out_size, void* d_ws, size_t ws_size,
                              hipStream_t stream) {
  (void)in_sizes; (void)n_in; (void)out_size;
  const float* x   = (const float*)d_in[0];
  const float* Wq  = (const float*)d_in[1];
  const float* bq  = (const float*)d_in[2];
  const float* Wk  = (const float*)d_in[3];
  const float* bk  = (const float*)d_in[4];
  const float* Wv  = (const float*)d_in[5];
  const float* bv  = (const float*)d_in[6];
  const float* Wss = (const float*)d_in[7];
  const float* bss = (const float*)d_in[8];
  float* out = (float*)d_out;

  const size_t SZ_XB   = (size_t)B_ * T_ * D_ * 2;        // 100663296
  const size_t SZ_WVT  = (size_t)D_ * D_ * 2;             // 1179648
  const size_t SZ_PART = (size_t)B_ * NCHUNK * D_ * 4;    // 6291456
  const size_t SZ_SSU  = (size_t)B_ * NK * 4;             // 98304
  const size_t SZ_NSSF = (size_t)B_ * NSS * D_ * 4;       // 393216
  const size_t SZ_NSST = (size_t)B_ * D_ * NSS * 2;       // 196608
  const size_t SZ_QB   = (size_t)B_ * NSS * 4;            // 512
  const size_t SZ_WQS  = (size_t)B_ * NSS * D_ * 2;       // 196608
  const size_t SMALL = SZ_WVT + SZ_PART + SZ_SSU + SZ_NSSF + SZ_NSST + SZ_QB + SZ_WQS;
  const size_t FULL = SZ_XB + SMALL;
  const bool big = ws_size >= FULL;

  char* ws = (char*)d_ws;
  size_t off = big ? SZ_XB : 0;
  u16*   xb    = (u16*)ws;
  u16*   wvT   = (u16*)(ws + off);   off += SZ_WVT;
  float* parts = (float*)(ws + off); off += SZ_PART;
  float* ssu   = (float*)(ws + off); off += SZ_SSU;
  float* nssf  = (float*)(ws + off); off += SZ_NSSF;
  u16*   nssT  = (u16*)(ws + off);   off += SZ_NSST;
  float* qbb   = (float*)(ws + off); off += SZ_QB;
  u16*   wqsT  = (u16*)(ws + off);   off += SZ_WQS;

  k_wvt<<<dim3(48, 48), 256, 0, stream>>>(Wv, wvT);
  if (big)
    k_conv_mean<true><<<dim3(NCHUNK, 16), 192, 0, stream>>>(x, xb, parts);
  else
    k_conv_mean<false><<<dim3(NCHUNK, 16), 192, 0, stream>>>(x, nullptr, parts);
  k_ssu<<<dim3(6, 16), 256, 0, stream>>>(parts, Wk, bk, ssu);
  k_nss<<<dim3(NSS, 16), 256, 0, stream>>>(x, ssu, Wss, bss, bq, out, nssf, nssT, qbb);
  k_wqs<<<dim3(24, 16), 256, 0, stream>>>(Wq, nssf, wqsT);
  if (big)
    k_main<true><<<3072, 256, 0, stream>>>(xb, x, wvT, wqsT, nssT, qbb, bv, out);
  else
    k_main<false><<<3072, 256, 0, stream>>>(nullptr, x, wvT, wqsT, nssT, qbb, bv, out);
}